// Round 1
// baseline (652.466 us; speedup 1.0000x reference)
//
#include <hip/hip_runtime.h>
#include <hip/hip_bf16.h>

#define CEPS 1e-8f

typedef __attribute__((ext_vector_type(8))) __bf16 bf16x8;
typedef __attribute__((ext_vector_type(4))) float f32x4;

__device__ __forceinline__ void gload_lds16(const void* g, void* l) {
  __builtin_amdgcn_global_load_lds((const __attribute__((address_space(1))) unsigned int*)g,
                                   (__attribute__((address_space(3))) unsigned int*)l, 16, 0, 0);
}

__device__ __forceinline__ float gelu_f(float v) {
  return 0.5f * v * (1.0f + erff(v * 0.70710678118654752f));
}

// ---------- magnitude + concat + row norm ----------
__global__ __launch_bounds__(256) void k_mag(const float* __restrict__ re, const float* __restrict__ im,
                                             float* __restrict__ mag, float* __restrict__ xcat,
                                             float* __restrict__ xn) {
  int row = blockIdx.x;  // 0..2047
  const float* r = re + (size_t)row * 512;
  const float* q = im + (size_t)row * 512;
  double ss = 0.0;
  for (int d = threadIdx.x; d < 512; d += 256) {
    float a = r[d], b = q[d];
    float s = __fadd_rn(__fmul_rn(a, a), __fmul_rn(b, b));  // match np rounding
    float m = __fsqrt_rn(s);
    mag[(size_t)row * 512 + d] = m;
    xcat[(size_t)row * 1024 + d] = a;
    xcat[(size_t)row * 1024 + 512 + d] = b;
    ss += (double)m * (double)m;
  }
  for (int off = 32; off; off >>= 1) ss += __shfl_xor(ss, off);
  __shared__ double red[4];
  int lane = threadIdx.x & 63, wave = threadIdx.x >> 6;
  if (lane == 0) red[wave] = ss;
  __syncthreads();
  if (threadIdx.x == 0) {
    double tot = red[0] + red[1] + red[2] + red[3];
    float n = (float)sqrt(tot);
    xn[row] = fmaxf(n, CEPS);
  }
}

// ---------- concept magnitude (transposed) + norms ----------
__global__ __launch_bounds__(256) void k_cmag(const float* __restrict__ cre, const float* __restrict__ cim,
                                              float* __restrict__ cmagT, float* __restrict__ yn) {
  int c = blockIdx.x;  // 0..999
  const float* r = cre + (size_t)c * 512;
  const float* q = cim + (size_t)c * 512;
  double ss = 0.0;
  for (int d = threadIdx.x; d < 512; d += 256) {
    float a = r[d], b = q[d];
    float s = __fadd_rn(__fmul_rn(a, a), __fmul_rn(b, b));
    float m = __fsqrt_rn(s);
    cmagT[(size_t)d * 1000 + c] = m;
    ss += (double)m * (double)m;
  }
  for (int off = 32; off; off >>= 1) ss += __shfl_xor(ss, off);
  __shared__ double red[4];
  int lane = threadIdx.x & 63, wave = threadIdx.x >> 6;
  if (lane == 0) red[wave] = ss;
  __syncthreads();
  if (threadIdx.x == 0) {
    double tot = red[0] + red[1] + red[2] + red[3];
    float n = (float)sqrt(tot);
    yn[c] = fmaxf(n, CEPS);
  }
}

// ---------- dots GEMM with f64 accumulation + cosine epilogue ----------
// A [M,K] f32, B [K,N] f32, out sims [M,N] f32
__global__ __launch_bounds__(256) void k_dots(const float* __restrict__ A, const float* __restrict__ Bm,
                                              float* __restrict__ Cm, int M, int N, int K, int ldc,
                                              const float* __restrict__ xn, const float* __restrict__ yn) {
  __shared__ float As[16][64];
  __shared__ float Bs[16][64];
  const int tid = threadIdx.x;
  const int m0 = blockIdx.y * 64, n0 = blockIdx.x * 64;
  const int tx = tid & 15, ty = tid >> 4;
  const int ar = tid >> 2, ak = (tid & 3) << 2;
  const int bk = tid >> 4, bn = (tid & 15) << 2;
  double acc[4][4] = {};
  for (int k0 = 0; k0 < K; k0 += 16) {
    float4 a4 = *(const float4*)(A + (size_t)(m0 + ar) * K + k0 + ak);
    As[ak + 0][ar] = a4.x; As[ak + 1][ar] = a4.y; As[ak + 2][ar] = a4.z; As[ak + 3][ar] = a4.w;
    float4 b4 = make_float4(0.f, 0.f, 0.f, 0.f);
    if (n0 + bn < N) b4 = *(const float4*)(Bm + (size_t)(k0 + bk) * N + n0 + bn);
    *(float4*)&Bs[bk][bn] = b4;
    __syncthreads();
#pragma unroll
    for (int kk = 0; kk < 16; ++kk) {
      float av[4], bv[4];
#pragma unroll
      for (int i = 0; i < 4; ++i) av[i] = As[kk][ty * 4 + i];
#pragma unroll
      for (int j = 0; j < 4; ++j) bv[j] = Bs[kk][tx * 4 + j];
#pragma unroll
      for (int i = 0; i < 4; ++i)
#pragma unroll
        for (int j = 0; j < 4; ++j)
          acc[i][j] += (double)av[i] * (double)bv[j];
    }
    __syncthreads();
  }
#pragma unroll
  for (int i = 0; i < 4; ++i) {
    int row = m0 + ty * 4 + i;
#pragma unroll
    for (int j = 0; j < 4; ++j) {
      int col = n0 + tx * 4 + j;
      if (col >= N) continue;
      double d = acc[i][j] / ((double)xn[row] * (double)yn[col]);
      Cm[(size_t)row * ldc + col] = (float)d;
    }
  }
}

// ---------- generic fp32 GEMM for MLP layers ----------
// EPI: 1 = bias+gelu f32 out, 3 = bias+gelu bf16 out
template <int EPI>
__global__ __launch_bounds__(256) void gemm_f32(const float* __restrict__ A, const float* __restrict__ Bm,
                                                void* __restrict__ Cout, int M, int N, int K, int ldc,
                                                const float* __restrict__ bias) {
  __shared__ float As[16][64];
  __shared__ float Bs[16][64];
  const int tid = threadIdx.x;
  const int m0 = blockIdx.y * 64, n0 = blockIdx.x * 64;
  const int tx = tid & 15, ty = tid >> 4;
  const int ar = tid >> 2, ak = (tid & 3) << 2;
  const int bk = tid >> 4, bn = (tid & 15) << 2;
  float acc[4][4] = {};
  for (int k0 = 0; k0 < K; k0 += 16) {
    float4 a4 = *(const float4*)(A + (size_t)(m0 + ar) * K + k0 + ak);
    As[ak + 0][ar] = a4.x; As[ak + 1][ar] = a4.y; As[ak + 2][ar] = a4.z; As[ak + 3][ar] = a4.w;
    float4 b4 = make_float4(0.f, 0.f, 0.f, 0.f);
    if (n0 + bn < N) b4 = *(const float4*)(Bm + (size_t)(k0 + bk) * N + n0 + bn);
    *(float4*)&Bs[bk][bn] = b4;
    __syncthreads();
#pragma unroll
    for (int kk = 0; kk < 16; ++kk) {
      float av[4], bv[4];
#pragma unroll
      for (int i = 0; i < 4; ++i) av[i] = As[kk][ty * 4 + i];
#pragma unroll
      for (int j = 0; j < 4; ++j) bv[j] = Bs[kk][tx * 4 + j];
#pragma unroll
      for (int i = 0; i < 4; ++i)
#pragma unroll
        for (int j = 0; j < 4; ++j)
          acc[i][j] = fmaf(av[i], bv[j], acc[i][j]);
    }
    __syncthreads();
  }
#pragma unroll
  for (int i = 0; i < 4; ++i) {
    int row = m0 + ty * 4 + i;
#pragma unroll
    for (int j = 0; j < 4; ++j) {
      int col = n0 + tx * 4 + j;
      if (col >= N) continue;
      float v = gelu_f(acc[i][j] + bias[col]);
      if (EPI == 1) ((float*)Cout)[(size_t)row * ldc + col] = v;
      else ((__hip_bfloat16*)Cout)[(size_t)row * ldc + col] = __float2bfloat16(v);
    }
  }
}

// ---------- top-5 per row (one wave per row) ----------
__global__ __launch_bounds__(256) void k_topk(const float* __restrict__ sims,
                                              float* __restrict__ top_sims, float* __restrict__ top_idx) {
  int lane = threadIdx.x & 63, wave = threadIdx.x >> 6;
  int row = blockIdx.x * 4 + wave;
  const float* s = sims + (size_t)row * 1000;
  float v[16];
  int idx[16];
#pragma unroll
  for (int t = 0; t < 16; ++t) {
    int c = lane + t * 64;
    if (c < 1000) { v[t] = s[c]; idx[t] = c; }
    else { v[t] = -1e30f; idx[t] = 1 << 20; }
  }
  for (int j = 0; j < 5; ++j) {
    float bv = -1e30f; int bi = 1 << 20;
#pragma unroll
    for (int t = 0; t < 16; ++t) {
      if (v[t] > bv || (v[t] == bv && idx[t] < bi)) { bv = v[t]; bi = idx[t]; }
    }
    float rv = bv; int ri = bi;
#pragma unroll
    for (int off = 32; off; off >>= 1) {
      float ov = __shfl_xor(rv, off);
      int oi = __shfl_xor(ri, off);
      if (ov > rv || (ov == rv && oi < ri)) { rv = ov; ri = oi; }
    }
    if (lane == 0) {
      top_sims[(size_t)row * 5 + j] = rv;
      top_idx[(size_t)row * 5 + j] = (float)ri;
    }
#pragma unroll
    for (int t = 0; t < 16; ++t)
      if (idx[t] == ri) v[t] = -1e30f;  // remove winner (static indexing)
  }
}

// ---------- W4 transpose + bf16 convert: W[K,N] f32 -> Wt[Npad,K] bf16 (zero-padded) ----------
__global__ __launch_bounds__(256) void k_w4t(const float* __restrict__ W, __hip_bfloat16* __restrict__ Wt,
                                             int K, int N) {
  __shared__ float t32[64][65];
  int n0 = blockIdx.x * 64, k0 = blockIdx.y * 64;
  int c = threadIdx.x & 63, r4 = threadIdx.x >> 6;
#pragma unroll
  for (int p = 0; p < 16; ++p) {
    int krow = p * 4 + r4;
    int n = n0 + c;
    float vv = 0.f;
    if (n < N) vv = W[(size_t)(k0 + krow) * N + n];
    t32[krow][c] = vv;
  }
  __syncthreads();
#pragma unroll
  for (int p = 0; p < 16; ++p) {
    int rn = p * 4 + r4;  // n offset within tile
    Wt[(size_t)(n0 + rn) * K + k0 + c] = __float2bfloat16(t32[c][rn]);
  }
}

// ---------- bf16 MFMA GEMM: C[M,N] = A[M,K] @ Bt[N,K]^T + bias ----------
__global__ __launch_bounds__(256) void gemm_mfma_bt(const __hip_bfloat16* __restrict__ A,
                                                    const __hip_bfloat16* __restrict__ Bt,
                                                    float* __restrict__ C, int M, int N, int K, int ldc,
                                                    const float* __restrict__ bias) {
  __shared__ short Al[128 * 32];
  __shared__ short Bl[128 * 32];
  const int tid = threadIdx.x, lane = tid & 63, wave = tid >> 6;
  const int m0 = blockIdx.y * 128, n0 = blockIdx.x * 128;
  const int wr = wave >> 1, wc = wave & 1;
  f32x4 acc[4][4];
  f32x4 zero4 = {0.f, 0.f, 0.f, 0.f};
#pragma unroll
  for (int i = 0; i < 4; ++i)
#pragma unroll
    for (int j = 0; j < 4; ++j) acc[i][j] = zero4;

  const short* Ag = (const short*)A;
  const short* Bg = (const short*)Bt;
  for (int k0 = 0; k0 < K; k0 += 32) {
#pragma unroll
    for (int s = 0; s < 2; ++s) {
      int seg = wave + s * 4;                  // 0..7
      int elem = seg * 512 + lane * 8;         // bf16 elements
      int row = elem >> 5, kk = elem & 31;
      gload_lds16(Ag + (size_t)(m0 + row) * K + k0 + kk, Al + elem);
      gload_lds16(Bg + (size_t)(n0 + row) * K + k0 + kk, Bl + elem);
    }
    __syncthreads();  // compiler drains vmcnt before barrier
    bf16x8 af[4], bfr[4];
    const int fr = lane & 15, fk = (lane >> 4) << 3;
#pragma unroll
    for (int i = 0; i < 4; ++i)
      af[i] = *(const bf16x8*)(Al + (wr * 64 + i * 16 + fr) * 32 + fk);
#pragma unroll
    for (int j = 0; j < 4; ++j)
      bfr[j] = *(const bf16x8*)(Bl + (wc * 64 + j * 16 + fr) * 32 + fk);
#pragma unroll
    for (int i = 0; i < 4; ++i)
#pragma unroll
      for (int j = 0; j < 4; ++j)
        acc[i][j] = __builtin_amdgcn_mfma_f32_16x16x32_bf16(af[i], bfr[j], acc[i][j], 0, 0, 0);
    __syncthreads();
  }
  const int fr = lane & 15, fq = lane >> 4;
#pragma unroll
  for (int j = 0; j < 4; ++j) {
    int col = n0 + wc * 64 + j * 16 + fr;
    if (col >= N) continue;
    float bv = bias[col];
#pragma unroll
    for (int i = 0; i < 4; ++i) {
      int rbase = m0 + wr * 64 + i * 16 + fq * 4;
#pragma unroll
      for (int r = 0; r < 4; ++r)
        C[(size_t)(rbase + r) * ldc + col] = acc[i][j][r] + bv;
    }
  }
}

extern "C" void kernel_launch(void* const* d_in, const int* in_sizes, int n_in,
                              void* d_out, int out_size, void* d_ws, size_t ws_size,
                              hipStream_t stream) {
  const float* sre = (const float*)d_in[0];
  const float* simg = (const float*)d_in[1];
  const float* cre = (const float*)d_in[2];
  const float* cim = (const float*)d_in[3];
  const float* W1 = (const float*)d_in[4];
  const float* b1 = (const float*)d_in[5];
  const float* W2 = (const float*)d_in[6];
  const float* b2 = (const float*)d_in[7];
  const float* W3 = (const float*)d_in[8];
  const float* b3 = (const float*)d_in[9];
  const float* W4 = (const float*)d_in[10];
  const float* b4 = (const float*)d_in[11];

  const int M = 2048, D = 512, Cc = 1000, V = 50000, K1 = 1024, H3 = 768;
  const int Npad = ((V + 127) / 128) * 128;  // 50048

  char* ws = (char*)d_ws;
  size_t off = 0;
  auto alloc = [&](size_t bytes) {
    char* p = ws + off;
    off = (off + bytes + 255) & ~(size_t)255;
    return p;
  };
  float* xcat = (float*)alloc((size_t)M * K1 * 4);
  float* mag = (float*)alloc((size_t)M * D * 4);
  float* cmagT = (float*)alloc((size_t)D * Cc * 4);
  float* xn = (float*)alloc((size_t)M * 4);
  float* yn = (float*)alloc((size_t)Cc * 4);
  float* simsb = (float*)alloc((size_t)M * Cc * 4);
  float* h1 = (float*)alloc((size_t)M * 512 * 4);
  float* h2 = (float*)alloc((size_t)M * 512 * 4);
  __hip_bfloat16* h3b = (__hip_bfloat16*)alloc((size_t)M * H3 * 2);
  __hip_bfloat16* w4t = (__hip_bfloat16*)alloc((size_t)Npad * H3 * 2);

  float* top_sims = (float*)d_out;
  float* top_idx = (float*)d_out + (size_t)M * 5;
  float* logits = (float*)d_out + (size_t)M * 5 * 2;

  k_cmag<<<dim3(Cc), dim3(256), 0, stream>>>(cre, cim, cmagT, yn);
  k_mag<<<dim3(M), dim3(256), 0, stream>>>(sre, simg, mag, xcat, xn);
  k_dots<<<dim3((Cc + 63) / 64, M / 64), dim3(256), 0, stream>>>(mag, cmagT, simsb, M, Cc, D, Cc, xn, yn);
  k_topk<<<dim3(M / 4), dim3(256), 0, stream>>>(simsb, top_sims, top_idx);
  gemm_f32<1><<<dim3(512 / 64, M / 64), dim3(256), 0, stream>>>(xcat, W1, (void*)h1, M, 512, K1, 512, b1);
  gemm_f32<1><<<dim3(512 / 64, M / 64), dim3(256), 0, stream>>>(h1, W2, (void*)h2, M, 512, 512, 512, b2);
  gemm_f32<3><<<dim3(768 / 64, M / 64), dim3(256), 0, stream>>>(h2, W3, (void*)h3b, M, 768, 512, 768, b3);
  k_w4t<<<dim3(Npad / 64, H3 / 64), dim3(256), 0, stream>>>(W4, w4t, H3, V);
  gemm_mfma_bt<<<dim3(Npad / 128, M / 128), dim3(256), 0, stream>>>(h3b, w4t, logits, M, V, H3, V, b4);
}

// Round 2
// 622.446 us; speedup vs baseline: 1.0482x; 1.0482x over previous
//
#include <hip/hip_runtime.h>
#include <hip/hip_bf16.h>

#define CEPS 1e-8f

typedef __attribute__((ext_vector_type(8))) __bf16 bf16x8;
typedef __attribute__((ext_vector_type(4))) float f32x4;

__device__ __forceinline__ void gload_lds16(const void* g, void* l) {
  __builtin_amdgcn_global_load_lds((const __attribute__((address_space(1))) unsigned int*)g,
                                   (__attribute__((address_space(3))) unsigned int*)l, 16, 0, 0);
}

__device__ __forceinline__ float gelu_f(float v) {
  return 0.5f * v * (1.0f + erff(v * 0.70710678118654752f));
}

// ---------- magnitude + concat + row norm ----------
__global__ __launch_bounds__(256) void k_mag(const float* __restrict__ re, const float* __restrict__ im,
                                             float* __restrict__ mag, float* __restrict__ xcat,
                                             float* __restrict__ xn) {
  int row = blockIdx.x;  // 0..2047
  const float* r = re + (size_t)row * 512;
  const float* q = im + (size_t)row * 512;
  double ss = 0.0;
  for (int d = threadIdx.x; d < 512; d += 256) {
    float a = r[d], b = q[d];
    float s = __fadd_rn(__fmul_rn(a, a), __fmul_rn(b, b));  // match np rounding
    float m = __fsqrt_rn(s);
    mag[(size_t)row * 512 + d] = m;
    xcat[(size_t)row * 1024 + d] = a;
    xcat[(size_t)row * 1024 + 512 + d] = b;
    ss += (double)m * (double)m;
  }
  for (int off = 32; off; off >>= 1) ss += __shfl_xor(ss, off);
  __shared__ double red[4];
  int lane = threadIdx.x & 63, wave = threadIdx.x >> 6;
  if (lane == 0) red[wave] = ss;
  __syncthreads();
  if (threadIdx.x == 0) {
    double tot = red[0] + red[1] + red[2] + red[3];
    float n = (float)sqrt(tot);
    xn[row] = fmaxf(n, CEPS);
  }
}

// ---------- concept magnitude (transposed) + norms ----------
__global__ __launch_bounds__(256) void k_cmag(const float* __restrict__ cre, const float* __restrict__ cim,
                                              float* __restrict__ cmagT, float* __restrict__ yn) {
  int c = blockIdx.x;  // 0..999
  const float* r = cre + (size_t)c * 512;
  const float* q = cim + (size_t)c * 512;
  double ss = 0.0;
  for (int d = threadIdx.x; d < 512; d += 256) {
    float a = r[d], b = q[d];
    float s = __fadd_rn(__fmul_rn(a, a), __fmul_rn(b, b));
    float m = __fsqrt_rn(s);
    cmagT[(size_t)d * 1000 + c] = m;
    ss += (double)m * (double)m;
  }
  for (int off = 32; off; off >>= 1) ss += __shfl_xor(ss, off);
  __shared__ double red[4];
  int lane = threadIdx.x & 63, wave = threadIdx.x >> 6;
  if (lane == 0) red[wave] = ss;
  __syncthreads();
  if (threadIdx.x == 0) {
    double tot = red[0] + red[1] + red[2] + red[3];
    float n = (float)sqrt(tot);
    yn[c] = fmaxf(n, CEPS);
  }
}

// ---------- dots GEMM with f64 accumulation + cosine epilogue ----------
__global__ __launch_bounds__(256) void k_dots(const float* __restrict__ A, const float* __restrict__ Bm,
                                              float* __restrict__ Cm, int M, int N, int K, int ldc,
                                              const float* __restrict__ xn, const float* __restrict__ yn) {
  __shared__ float As[16][64];
  __shared__ float Bs[16][64];
  const int tid = threadIdx.x;
  const int m0 = blockIdx.y * 64, n0 = blockIdx.x * 64;
  const int tx = tid & 15, ty = tid >> 4;
  const int ar = tid >> 2, ak = (tid & 3) << 2;
  const int bk = tid >> 4, bn = (tid & 15) << 2;
  double acc[4][4] = {};
  for (int k0 = 0; k0 < K; k0 += 16) {
    float4 a4 = *(const float4*)(A + (size_t)(m0 + ar) * K + k0 + ak);
    As[ak + 0][ar] = a4.x; As[ak + 1][ar] = a4.y; As[ak + 2][ar] = a4.z; As[ak + 3][ar] = a4.w;
    float4 b4 = make_float4(0.f, 0.f, 0.f, 0.f);
    if (n0 + bn < N) b4 = *(const float4*)(Bm + (size_t)(k0 + bk) * N + n0 + bn);
    *(float4*)&Bs[bk][bn] = b4;
    __syncthreads();
#pragma unroll
    for (int kk = 0; kk < 16; ++kk) {
      float av[4], bv[4];
#pragma unroll
      for (int i = 0; i < 4; ++i) av[i] = As[kk][ty * 4 + i];
#pragma unroll
      for (int j = 0; j < 4; ++j) bv[j] = Bs[kk][tx * 4 + j];
#pragma unroll
      for (int i = 0; i < 4; ++i)
#pragma unroll
        for (int j = 0; j < 4; ++j)
          acc[i][j] += (double)av[i] * (double)bv[j];
    }
    __syncthreads();
  }
#pragma unroll
  for (int i = 0; i < 4; ++i) {
    int row = m0 + ty * 4 + i;
#pragma unroll
    for (int j = 0; j < 4; ++j) {
      int col = n0 + tx * 4 + j;
      if (col >= N) continue;
      double d = acc[i][j] / ((double)xn[row] * (double)yn[col]);
      Cm[(size_t)row * ldc + col] = (float)d;
    }
  }
}

// ---------- generic fp32 GEMM for MLP layers ----------
template <int EPI>  // 1 = bias+gelu f32 out, 3 = bias+gelu bf16 out
__global__ __launch_bounds__(256) void gemm_f32(const float* __restrict__ A, const float* __restrict__ Bm,
                                                void* __restrict__ Cout, int M, int N, int K, int ldc,
                                                const float* __restrict__ bias) {
  __shared__ float As[16][64];
  __shared__ float Bs[16][64];
  const int tid = threadIdx.x;
  const int m0 = blockIdx.y * 64, n0 = blockIdx.x * 64;
  const int tx = tid & 15, ty = tid >> 4;
  const int ar = tid >> 2, ak = (tid & 3) << 2;
  const int bk = tid >> 4, bn = (tid & 15) << 2;
  float acc[4][4] = {};
  for (int k0 = 0; k0 < K; k0 += 16) {
    float4 a4 = *(const float4*)(A + (size_t)(m0 + ar) * K + k0 + ak);
    As[ak + 0][ar] = a4.x; As[ak + 1][ar] = a4.y; As[ak + 2][ar] = a4.z; As[ak + 3][ar] = a4.w;
    float4 b4 = make_float4(0.f, 0.f, 0.f, 0.f);
    if (n0 + bn < N) b4 = *(const float4*)(Bm + (size_t)(k0 + bk) * N + n0 + bn);
    *(float4*)&Bs[bk][bn] = b4;
    __syncthreads();
#pragma unroll
    for (int kk = 0; kk < 16; ++kk) {
      float av[4], bv[4];
#pragma unroll
      for (int i = 0; i < 4; ++i) av[i] = As[kk][ty * 4 + i];
#pragma unroll
      for (int j = 0; j < 4; ++j) bv[j] = Bs[kk][tx * 4 + j];
#pragma unroll
      for (int i = 0; i < 4; ++i)
#pragma unroll
        for (int j = 0; j < 4; ++j)
          acc[i][j] = fmaf(av[i], bv[j], acc[i][j]);
    }
    __syncthreads();
  }
#pragma unroll
  for (int i = 0; i < 4; ++i) {
    int row = m0 + ty * 4 + i;
#pragma unroll
    for (int j = 0; j < 4; ++j) {
      int col = n0 + tx * 4 + j;
      if (col >= N) continue;
      float v = gelu_f(acc[i][j] + bias[col]);
      if (EPI == 1) ((float*)Cout)[(size_t)row * ldc + col] = v;
      else ((__hip_bfloat16*)Cout)[(size_t)row * ldc + col] = __float2bfloat16(v);
    }
  }
}

// ---------- top-5 per row (one wave per row) ----------
__global__ __launch_bounds__(256) void k_topk(const float* __restrict__ sims,
                                              float* __restrict__ top_sims, float* __restrict__ top_idx) {
  int lane = threadIdx.x & 63, wave = threadIdx.x >> 6;
  int row = blockIdx.x * 4 + wave;
  const float* s = sims + (size_t)row * 1000;
  float v[16];
  int idx[16];
#pragma unroll
  for (int t = 0; t < 16; ++t) {
    int c = lane + t * 64;
    if (c < 1000) { v[t] = s[c]; idx[t] = c; }
    else { v[t] = -1e30f; idx[t] = 1 << 20; }
  }
  for (int j = 0; j < 5; ++j) {
    float bv = -1e30f; int bi = 1 << 20;
#pragma unroll
    for (int t = 0; t < 16; ++t) {
      if (v[t] > bv || (v[t] == bv && idx[t] < bi)) { bv = v[t]; bi = idx[t]; }
    }
    float rv = bv; int ri = bi;
#pragma unroll
    for (int off = 32; off; off >>= 1) {
      float ov = __shfl_xor(rv, off);
      int oi = __shfl_xor(ri, off);
      if (ov > rv || (ov == rv && oi < ri)) { rv = ov; ri = oi; }
    }
    if (lane == 0) {
      top_sims[(size_t)row * 5 + j] = rv;
      top_idx[(size_t)row * 5 + j] = (float)ri;
    }
#pragma unroll
    for (int t = 0; t < 16; ++t)
      if (idx[t] == ri) v[t] = -1e30f;
  }
}

// ---------- W4 transpose + bf16 convert: W[K,N] f32 -> Wt[Npad,K] bf16 (zero-padded) ----------
__global__ __launch_bounds__(256) void k_w4t(const float* __restrict__ W, __hip_bfloat16* __restrict__ Wt,
                                             int K, int N) {
  __shared__ float t32[64][65];
  int n0 = blockIdx.x * 64, k0 = blockIdx.y * 64;
  int c = threadIdx.x & 63, r4 = threadIdx.x >> 6;
#pragma unroll
  for (int p = 0; p < 16; ++p) {
    int krow = p * 4 + r4;
    int n = n0 + c;
    float vv = 0.f;
    if (n < N) vv = W[(size_t)(k0 + krow) * N + n];
    t32[krow][c] = vv;
  }
  __syncthreads();
#pragma unroll
  for (int p = 0; p < 16; ++p) {
    int rn = p * 4 + r4;
    Wt[(size_t)(n0 + rn) * K + k0 + c] = __float2bfloat16(t32[c][rn]);
  }
}

// ---------- 256x256 8-phase bf16 MFMA GEMM: C[M,N] = A[M,K] @ Bt[Nrows,K]^T + bias ----------
// 512 threads, 8 waves (2Mx4N), BK=64, double-buffered 128 KiB LDS.
// T2 XOR swizzle (chunk ^= row&7) pre-applied on global source (gload_lds dest linear) and on ds_read.
// Counted vmcnt(4) only at phases 4/8; raw s_barrier + sched_barrier(0) per phase; setprio(1) around MFMA.
#define PHASE_END() do { __builtin_amdgcn_sched_barrier(0); __builtin_amdgcn_s_barrier(); __builtin_amdgcn_sched_barrier(0); } while (0)

__global__ __launch_bounds__(512, 2) void gemm_mfma8(const __hip_bfloat16* __restrict__ A,
                                                     const __hip_bfloat16* __restrict__ Bt,
                                                     float* __restrict__ C, int N, int K, int ldc,
                                                     const float* __restrict__ bias,
                                                     int mtiles, int ntiles) {
  __shared__ short As[2][16384];  // [buf][256 rows x 64 cols]
  __shared__ short Bs[2][16384];
  const int tid = threadIdx.x, lane = tid & 63, wave = tid >> 6;
  const int wm = wave >> 2, wn = wave & 3;

  // XCD-chunked bijective swizzle (nwg % 8 == 0) with M-inner decomposition for B-panel L2 sharing
  const int nwg = mtiles * ntiles;
  const int cpx = nwg >> 3;
  const int swz = (blockIdx.x & 7) * cpx + (blockIdx.x >> 3);
  const int mt = swz % mtiles;
  const int ntile = swz / mtiles;
  const int m0 = mt * 256, n0 = ntile * 256;

  const short* Ag = (const short*)A;
  const short* Bg = (const short*)Bt;

  f32x4 acc[8][4];
  f32x4 z4 = {0.f, 0.f, 0.f, 0.f};
#pragma unroll
  for (int i = 0; i < 8; ++i)
#pragma unroll
    for (int j = 0; j < 4; ++j) acc[i][j] = z4;

  // ---- staging: one half-tile (128 rows x 64 cols) = 2 x gload_lds16 per thread ----
  auto stageA = [&](int kt, int h) {
    const int buf = kt & 1, k0 = kt * 64;
#pragma unroll
    for (int r = 0; r < 2; ++r) {
      int idx = r * 512 + tid;
      int row = h * 128 + (idx >> 3);
      int ch = (idx & 7) ^ (row & 7);  // inverse-swizzled global source
      gload_lds16(Ag + (size_t)(m0 + row) * K + k0 + ch * 8, &As[buf][row * 64 + (idx & 7) * 8]);
    }
  };
  auto stageB = [&](int kt, int h) {
    const int buf = kt & 1, k0 = kt * 64;
#pragma unroll
    for (int r = 0; r < 2; ++r) {
      int idx = r * 512 + tid;
      int row = h * 128 + (idx >> 3);
      int ch = (idx & 7) ^ (row & 7);
      gload_lds16(Bg + (size_t)(n0 + row) * K + k0 + ch * 8, &Bs[buf][row * 64 + (idx & 7) * 8]);
    }
  };

  bf16x8 af[4][2], bf0[2][2], bf1[2][2];
  auto readA = [&](int buf, int mh) {
#pragma unroll
    for (int q = 0; q < 4; ++q) {
      int row = wm * 128 + (mh * 4 + q) * 16 + (lane & 15);
#pragma unroll
      for (int ks = 0; ks < 2; ++ks) {
        int ch = (ks * 4 + (lane >> 4)) ^ (row & 7);  // swizzled read
        af[q][ks] = *(const bf16x8*)(&As[buf][row * 64 + ch * 8]);
      }
    }
  };
  auto readB = [&](int buf, int nh, bf16x8 bfr[2][2]) {
#pragma unroll
    for (int p = 0; p < 2; ++p) {
      int row = wn * 64 + (nh * 2 + p) * 16 + (lane & 15);
#pragma unroll
      for (int ks = 0; ks < 2; ++ks) {
        int ch = (ks * 4 + (lane >> 4)) ^ (row & 7);
        bfr[p][ks] = *(const bf16x8*)(&Bs[buf][row * 64 + ch * 8]);
      }
    }
  };
  auto domfma = [&](int mh, int p0, bf16x8 bfr[2][2]) {
    __builtin_amdgcn_s_setprio(1);
#pragma unroll
    for (int ks = 0; ks < 2; ++ks)
#pragma unroll
      for (int q = 0; q < 4; ++q)
#pragma unroll
        for (int p = 0; p < 2; ++p)
          acc[mh * 4 + q][p0 + p] =
              __builtin_amdgcn_mfma_f32_16x16x32_bf16(af[q][ks], bfr[p][ks], acc[mh * 4 + q][p0 + p], 0, 0, 0);
    __builtin_amdgcn_s_setprio(0);
  };

  const int nt = K / 64;      // 12 (even, >= 2)
  const int iters = nt / 2;   // 6

  // ---- prologue: tile0 (4 halves) + tile1 B (2 halves); wait tile0 landed (<=4 outstanding) ----
  stageB(0, 0); stageB(0, 1); stageA(0, 0); stageA(0, 1);
  stageB(1, 0); stageB(1, 1);
  asm volatile("s_waitcnt vmcnt(4)" ::: "memory");
  PHASE_END();

  for (int i = 0; i < iters; ++i) {
    const int t1 = 2 * i + 1, t2 = 2 * i + 2, t3 = 2 * i + 3;
    const bool has2 = (t2 < nt);  // nt even => t3 < nt iff has2
    // phase 1: Q(m0,n0) of buf0 | stage A-h0(t1)->buf1   (buf1.A reads finished last iter ph7)
    stageA(t1, 0);
    readA(0, 0);
    readB(0, 0, bf0);
    domfma(0, 0, bf0);
    PHASE_END();
    // phase 2: Q(m0,n1) | stage A-h1(t1)->buf1
    stageA(t1, 1);
    readB(0, 1, bf1);
    domfma(0, 2, bf1);
    PHASE_END();
    // phase 3: Q(m1,n1) | stage B-h0(t2)->buf0  (buf0.B reads finished end of ph2)
    if (has2) stageB(t2, 0);
    readA(0, 1);
    domfma(1, 2, bf1);
    PHASE_END();
    // phase 4: Q(m1,n0) | stage B-h1(t2)->buf0; wait tile t1 landed (allow ph3/ph4 = 4 loads)
    if (has2) stageB(t2, 1);
    readB(0, 0, bf0);
    domfma(1, 0, bf0);
    if (has2) asm volatile("s_waitcnt vmcnt(4)" ::: "memory");
    else      asm volatile("s_waitcnt vmcnt(0)" ::: "memory");
    PHASE_END();
    // phase 5: Q(m0,n0) of buf1 | stage A-h0(t2)->buf0  (buf0.A reads finished end of ph3/4)
    if (has2) stageA(t2, 0);
    readA(1, 0);
    readB(1, 0, bf0);
    domfma(0, 0, bf0);
    PHASE_END();
    // phase 6: Q(m0,n1) | stage A-h1(t2)->buf0
    if (has2) stageA(t2, 1);
    readB(1, 1, bf1);
    domfma(0, 2, bf1);
    PHASE_END();
    // phase 7: Q(m1,n1) | stage B-h0(t3)->buf1  (buf1.B reads finished end of ph6)
    if (has2) stageB(t3, 0);
    readA(1, 1);
    domfma(1, 2, bf1);
    PHASE_END();
    // phase 8: Q(m1,n0) | stage B-h1(t3)->buf1; wait tile t2 landed (allow ph7/ph8 = 4 loads)
    if (has2) stageB(t3, 1);
    readB(1, 0, bf0);
    domfma(1, 0, bf0);
    if (has2) asm volatile("s_waitcnt vmcnt(4)" ::: "memory");
    PHASE_END();
  }

  // ---- epilogue: bias + store (cols >= N masked) ----
#pragma unroll
  for (int mi = 0; mi < 8; ++mi) {
    int rbase = m0 + wm * 128 + mi * 16 + (lane >> 4) * 4;
#pragma unroll
    for (int nj = 0; nj < 4; ++nj) {
      int col = n0 + wn * 64 + nj * 16 + (lane & 15);
      if (col < N) {
        float bv = bias[col];
#pragma unroll
        for (int r = 0; r < 4; ++r)
          C[(size_t)(rbase + r) * ldc + col] = acc[mi][nj][r] + bv;
      }
    }
  }
}

extern "C" void kernel_launch(void* const* d_in, const int* in_sizes, int n_in,
                              void* d_out, int out_size, void* d_ws, size_t ws_size,
                              hipStream_t stream) {
  const float* sre = (const float*)d_in[0];
  const float* simg = (const float*)d_in[1];
  const float* cre = (const float*)d_in[2];
  const float* cim = (const float*)d_in[3];
  const float* W1 = (const float*)d_in[4];
  const float* b1 = (const float*)d_in[5];
  const float* W2 = (const float*)d_in[6];
  const float* b2 = (const float*)d_in[7];
  const float* W3 = (const float*)d_in[8];
  const float* b3 = (const float*)d_in[9];
  const float* W4 = (const float*)d_in[10];
  const float* b4 = (const float*)d_in[11];

  const int M = 2048, D = 512, Cc = 1000, V = 50000, K1 = 1024, H3 = 768;
  const int MT = M / 256;                       // 8
  const int NT = (V + 255) / 256;               // 196
  const int Npad2 = NT * 256;                   // 50176

  char* ws = (char*)d_ws;
  size_t off = 0;
  auto alloc = [&](size_t bytes) {
    char* p = ws + off;
    off = (off + bytes + 255) & ~(size_t)255;
    return p;
  };
  float* xcat = (float*)alloc((size_t)M * K1 * 4);
  float* mag = (float*)alloc((size_t)M * D * 4);
  float* cmagT = (float*)alloc((size_t)D * Cc * 4);
  float* xn = (float*)alloc((size_t)M * 4);
  float* yn = (float*)alloc((size_t)Cc * 4);
  float* simsb = (float*)alloc((size_t)M * Cc * 4);
  float* h1 = (float*)alloc((size_t)M * 512 * 4);
  float* h2 = (float*)alloc((size_t)M * 512 * 4);
  __hip_bfloat16* h3b = (__hip_bfloat16*)alloc((size_t)M * H3 * 2);
  __hip_bfloat16* w4t = (__hip_bfloat16*)alloc((size_t)Npad2 * H3 * 2);

  float* top_sims = (float*)d_out;
  float* top_idx = (float*)d_out + (size_t)M * 5;
  float* logits = (float*)d_out + (size_t)M * 5 * 2;

  k_cmag<<<dim3(Cc), dim3(256), 0, stream>>>(cre, cim, cmagT, yn);
  k_mag<<<dim3(M), dim3(256), 0, stream>>>(sre, simg, mag, xcat, xn);
  k_dots<<<dim3((Cc + 63) / 64, M / 64), dim3(256), 0, stream>>>(mag, cmagT, simsb, M, Cc, D, Cc, xn, yn);
  k_topk<<<dim3(M / 4), dim3(256), 0, stream>>>(simsb, top_sims, top_idx);
  gemm_f32<1><<<dim3(512 / 64, M / 64), dim3(256), 0, stream>>>(xcat, W1, (void*)h1, M, 512, K1, 512, b1);
  gemm_f32<1><<<dim3(512 / 64, M / 64), dim3(256), 0, stream>>>(h1, W2, (void*)h2, M, 512, 512, 512, b2);
  gemm_f32<3><<<dim3(768 / 64, M / 64), dim3(256), 0, stream>>>(h2, W3, (void*)h3b, M, 768, 512, 768, b3);
  k_w4t<<<dim3(Npad2 / 64, H3 / 64), dim3(256), 0, stream>>>(W4, w4t, H3, V);
  gemm_mfma8<<<dim3(MT * NT), dim3(512), 0, stream>>>(h3b, w4t, logits, V, H3, V, b4, MT, NT);
}

// Round 3
// 490.925 us; speedup vs baseline: 1.3291x; 1.2679x over previous
//
#include <hip/hip_runtime.h>
#include <hip/hip_bf16.h>

#define CEPS 1e-8f

typedef __attribute__((ext_vector_type(8))) __bf16 bf16x8;
typedef __attribute__((ext_vector_type(4))) float f32x4;

__device__ __forceinline__ void gload_lds16(const void* g, void* l) {
  __builtin_amdgcn_global_load_lds((const __attribute__((address_space(1))) unsigned int*)g,
                                   (__attribute__((address_space(3))) unsigned int*)l, 16, 0, 0);
}

__device__ __forceinline__ float gelu_f(float v) {
  return 0.5f * v * (1.0f + erff(v * 0.70710678118654752f));
}

// ---------- magnitude + concat(bf16) + row norm ----------
__global__ __launch_bounds__(256) void k_mag(const float* __restrict__ re, const float* __restrict__ im,
                                             float* __restrict__ mag, __hip_bfloat16* __restrict__ xcat,
                                             float* __restrict__ xn) {
  int row = blockIdx.x;  // 0..2047
  const float* r = re + (size_t)row * 512;
  const float* q = im + (size_t)row * 512;
  double ss = 0.0;
  for (int d = threadIdx.x; d < 512; d += 256) {
    float a = r[d], b = q[d];
    float s = __fadd_rn(__fmul_rn(a, a), __fmul_rn(b, b));  // match np rounding
    float m = __fsqrt_rn(s);
    mag[(size_t)row * 512 + d] = m;
    xcat[(size_t)row * 1024 + d] = __float2bfloat16(a);
    xcat[(size_t)row * 1024 + 512 + d] = __float2bfloat16(b);
    ss += (double)m * (double)m;
  }
  for (int off = 32; off; off >>= 1) ss += __shfl_xor(ss, off);
  __shared__ double red[4];
  int lane = threadIdx.x & 63, wave = threadIdx.x >> 6;
  if (lane == 0) red[wave] = ss;
  __syncthreads();
  if (threadIdx.x == 0) {
    double tot = red[0] + red[1] + red[2] + red[3];
    float n = (float)sqrt(tot);
    xn[row] = fmaxf(n, CEPS);
  }
}

// ---------- concept magnitude (transposed) + norms ----------
__global__ __launch_bounds__(256) void k_cmag(const float* __restrict__ cre, const float* __restrict__ cim,
                                              float* __restrict__ cmagT, float* __restrict__ yn) {
  int c = blockIdx.x;  // 0..999
  const float* r = cre + (size_t)c * 512;
  const float* q = cim + (size_t)c * 512;
  double ss = 0.0;
  for (int d = threadIdx.x; d < 512; d += 256) {
    float a = r[d], b = q[d];
    float s = __fadd_rn(__fmul_rn(a, a), __fmul_rn(b, b));
    float m = __fsqrt_rn(s);
    cmagT[(size_t)d * 1000 + c] = m;
    ss += (double)m * (double)m;
  }
  for (int off = 32; off; off >>= 1) ss += __shfl_xor(ss, off);
  __shared__ double red[4];
  int lane = threadIdx.x & 63, wave = threadIdx.x >> 6;
  if (lane == 0) red[wave] = ss;
  __syncthreads();
  if (threadIdx.x == 0) {
    double tot = red[0] + red[1] + red[2] + red[3];
    float n = (float)sqrt(tot);
    yn[c] = fmaxf(n, CEPS);
  }
}

// ---------- dots GEMM with f64 accumulation + cosine epilogue ----------
__global__ __launch_bounds__(256) void k_dots(const float* __restrict__ A, const float* __restrict__ Bm,
                                              float* __restrict__ Cm, int M, int N, int K, int ldc,
                                              const float* __restrict__ xn, const float* __restrict__ yn) {
  __shared__ float As[16][64];
  __shared__ float Bs[16][64];
  const int tid = threadIdx.x;
  const int m0 = blockIdx.y * 64, n0 = blockIdx.x * 64;
  const int tx = tid & 15, ty = tid >> 4;
  const int ar = tid >> 2, ak = (tid & 3) << 2;
  const int bk = tid >> 4, bn = (tid & 15) << 2;
  double acc[4][4] = {};
  for (int k0 = 0; k0 < K; k0 += 16) {
    float4 a4 = *(const float4*)(A + (size_t)(m0 + ar) * K + k0 + ak);
    As[ak + 0][ar] = a4.x; As[ak + 1][ar] = a4.y; As[ak + 2][ar] = a4.z; As[ak + 3][ar] = a4.w;
    float4 b4 = make_float4(0.f, 0.f, 0.f, 0.f);
    if (n0 + bn < N) b4 = *(const float4*)(Bm + (size_t)(k0 + bk) * N + n0 + bn);
    *(float4*)&Bs[bk][bn] = b4;
    __syncthreads();
#pragma unroll
    for (int kk = 0; kk < 16; ++kk) {
      float av[4], bv[4];
#pragma unroll
      for (int i = 0; i < 4; ++i) av[i] = As[kk][ty * 4 + i];
#pragma unroll
      for (int j = 0; j < 4; ++j) bv[j] = Bs[kk][tx * 4 + j];
#pragma unroll
      for (int i = 0; i < 4; ++i)
#pragma unroll
        for (int j = 0; j < 4; ++j)
          acc[i][j] += (double)av[i] * (double)bv[j];
    }
    __syncthreads();
  }
#pragma unroll
  for (int i = 0; i < 4; ++i) {
    int row = m0 + ty * 4 + i;
#pragma unroll
    for (int j = 0; j < 4; ++j) {
      int col = n0 + tx * 4 + j;
      if (col >= N) continue;
      double d = acc[i][j] / ((double)xn[row] * (double)yn[col]);
      Cm[(size_t)row * ldc + col] = (float)d;
    }
  }
}

// ---------- top-5 per row (one wave per row) ----------
__global__ __launch_bounds__(256) void k_topk(const float* __restrict__ sims,
                                              float* __restrict__ top_sims, float* __restrict__ top_idx) {
  int lane = threadIdx.x & 63, wave = threadIdx.x >> 6;
  int row = blockIdx.x * 4 + wave;
  const float* s = sims + (size_t)row * 1000;
  float v[16];
  int idx[16];
#pragma unroll
  for (int t = 0; t < 16; ++t) {
    int c = lane + t * 64;
    if (c < 1000) { v[t] = s[c]; idx[t] = c; }
    else { v[t] = -1e30f; idx[t] = 1 << 20; }
  }
  for (int j = 0; j < 5; ++j) {
    float bv = -1e30f; int bi = 1 << 20;
#pragma unroll
    for (int t = 0; t < 16; ++t) {
      if (v[t] > bv || (v[t] == bv && idx[t] < bi)) { bv = v[t]; bi = idx[t]; }
    }
    float rv = bv; int ri = bi;
#pragma unroll
    for (int off = 32; off; off >>= 1) {
      float ov = __shfl_xor(rv, off);
      int oi = __shfl_xor(ri, off);
      if (ov > rv || (ov == rv && oi < ri)) { rv = ov; ri = oi; }
    }
    if (lane == 0) {
      top_sims[(size_t)row * 5 + j] = rv;
      top_idx[(size_t)row * 5 + j] = (float)ri;
    }
#pragma unroll
    for (int t = 0; t < 16; ++t)
      if (idx[t] == ri) v[t] = -1e30f;
  }
}

// ---------- generic transpose + bf16 convert: W[K,N] f32 -> Wt[Nout rows][K] bf16 (zero-pad n>=N) ----------
// grid (Nout/64, K/64); requires N%4==0, K%4==0.
__global__ __launch_bounds__(256) void k_tr(const float* __restrict__ W, __hip_bfloat16* __restrict__ Wt,
                                            int K, int N) {
  __shared__ float t32[64][65];
  int n0 = blockIdx.x * 64, k0 = blockIdx.y * 64;
  int tid = threadIdx.x;
  {
    int nc = tid & 15, kr4 = tid >> 4;
#pragma unroll
    for (int p = 0; p < 4; ++p) {
      int kr = p * 16 + kr4;
      int n = n0 + nc * 4;
      float4 v = make_float4(0.f, 0.f, 0.f, 0.f);
      if (n < N) v = *(const float4*)(W + (size_t)(k0 + kr) * N + n);
      t32[kr][nc * 4 + 0] = v.x; t32[kr][nc * 4 + 1] = v.y;
      t32[kr][nc * 4 + 2] = v.z; t32[kr][nc * 4 + 3] = v.w;
    }
  }
  __syncthreads();
  {
    int kc = tid & 15, nr4 = tid >> 4;
#pragma unroll
    for (int p = 0; p < 4; ++p) {
      int nr = p * 16 + nr4;
      ushort4 o;
      {
        __hip_bfloat16 h0 = __float2bfloat16(t32[kc * 4 + 0][nr]);
        __hip_bfloat16 h1 = __float2bfloat16(t32[kc * 4 + 1][nr]);
        __hip_bfloat16 h2 = __float2bfloat16(t32[kc * 4 + 2][nr]);
        __hip_bfloat16 h3 = __float2bfloat16(t32[kc * 4 + 3][nr]);
        o.x = *(unsigned short*)&h0; o.y = *(unsigned short*)&h1;
        o.z = *(unsigned short*)&h2; o.w = *(unsigned short*)&h3;
      }
      *(ushort4*)((unsigned short*)Wt + (size_t)(n0 + nr) * K + k0 + kc * 4) = o;
    }
  }
}

// ---------- 128x128 bf16 MFMA GEMM with gelu+bf16 epilogue (MLP layers) ----------
__global__ __launch_bounds__(256) void gemm_mfma_bt(const __hip_bfloat16* __restrict__ A,
                                                    const __hip_bfloat16* __restrict__ Bt,
                                                    __hip_bfloat16* __restrict__ C, int M, int N, int K,
                                                    int ldc, const float* __restrict__ bias) {
  __shared__ short Al[128 * 32];
  __shared__ short Bl[128 * 32];
  const int tid = threadIdx.x, lane = tid & 63, wave = tid >> 6;
  const int m0 = blockIdx.y * 128, n0 = blockIdx.x * 128;
  const int wr = wave >> 1, wc = wave & 1;
  f32x4 acc[4][4];
  f32x4 zero4 = {0.f, 0.f, 0.f, 0.f};
#pragma unroll
  for (int i = 0; i < 4; ++i)
#pragma unroll
    for (int j = 0; j < 4; ++j) acc[i][j] = zero4;

  const short* Ag = (const short*)A;
  const short* Bg = (const short*)Bt;
  for (int k0 = 0; k0 < K; k0 += 32) {
#pragma unroll
    for (int s = 0; s < 2; ++s) {
      int seg = wave + s * 4;
      int elem = seg * 512 + lane * 8;
      int row = elem >> 5, kk = elem & 31;
      gload_lds16(Ag + (size_t)(m0 + row) * K + k0 + kk, Al + elem);
      gload_lds16(Bg + (size_t)(n0 + row) * K + k0 + kk, Bl + elem);
    }
    __syncthreads();
    bf16x8 af[4], bfr[4];
    const int fr = lane & 15, fk = (lane >> 4) << 3;
#pragma unroll
    for (int i = 0; i < 4; ++i)
      af[i] = *(const bf16x8*)(Al + (wr * 64 + i * 16 + fr) * 32 + fk);
#pragma unroll
    for (int j = 0; j < 4; ++j)
      bfr[j] = *(const bf16x8*)(Bl + (wc * 64 + j * 16 + fr) * 32 + fk);
#pragma unroll
    for (int i = 0; i < 4; ++i)
#pragma unroll
      for (int j = 0; j < 4; ++j)
        acc[i][j] = __builtin_amdgcn_mfma_f32_16x16x32_bf16(af[i], bfr[j], acc[i][j], 0, 0, 0);
    __syncthreads();
  }
  const int fr = lane & 15, fq = lane >> 4;
#pragma unroll
  for (int j = 0; j < 4; ++j) {
    int col = n0 + wc * 64 + j * 16 + fr;
    if (col >= N) continue;
    float bv = bias[col];
#pragma unroll
    for (int i = 0; i < 4; ++i) {
      int rbase = m0 + wr * 64 + i * 16 + fq * 4;
#pragma unroll
      for (int r = 0; r < 4; ++r)
        C[(size_t)(rbase + r) * ldc + col] = __float2bfloat16(gelu_f(acc[i][j][r] + bv));
    }
  }
}

// ---------- persistent 256x256 8-phase bf16 MFMA GEMM (final layer) ----------
// Hardcoded: M=2048 (8 mtiles), N=50000 (196 ntiles of 256, padded B rows), K=768 (12 K-tiles).
// 256 blocks (1/CU), 512 thr, 8 waves (2Mx4N). Each block owns 6-7 contiguous tiles
// (ntile-major order); XCD-exclusive ranges via (bid&7)*32+(bid>>3). The 8-phase
// double-buffered schedule runs on a GLOBAL K-tile counter: a tile's last-iteration
// stage slots prefetch the next tile's first K-tiles (nt=12 even keeps parity and
// vmcnt cadence unchanged); acc dump overlaps the next tile's in-flight loads.
#define PHASE_END() do { __builtin_amdgcn_sched_barrier(0); __builtin_amdgcn_s_barrier(); __builtin_amdgcn_sched_barrier(0); } while (0)

__global__ __launch_bounds__(512, 2) void gemm_mfma8(const __hip_bfloat16* __restrict__ A,
                                                     const __hip_bfloat16* __restrict__ Bt,
                                                     float* __restrict__ C,
                                                     const float* __restrict__ bias) {
  const int NQ = 6, NR = 32;      // 1568 tiles over 256 blocks
  const int KNT = 12;             // K/64
  const int Kd = 768, Nd = 50000, ldc = 50000;
  __shared__ short As[2][16384];  // [buf][256 rows x 64 cols]
  __shared__ short Bs[2][16384];
  const int tid = threadIdx.x, lane = tid & 63, wave = tid >> 6;
  const int wm = wave >> 2, wn = wave & 3;

  const int rangeIdx = (blockIdx.x & 7) * 32 + (blockIdx.x >> 3);
  const int t0 = rangeIdx * NQ + (rangeIdx < NR ? rangeIdx : NR);
  const int T = NQ + (rangeIdx < NR ? 1 : 0);
  const int G = T * KNT;          // global K-tile count for this block (even)

  const short* Ag = (const short*)A;
  const short* Bg = (const short*)Bt;

  f32x4 acc[8][4];
  f32x4 z4 = {0.f, 0.f, 0.f, 0.f};
#pragma unroll
  for (int i = 0; i < 8; ++i)
#pragma unroll
    for (int j = 0; j < 4; ++j) acc[i][j] = z4;

  // stage one half-tile (128 rows x 64 cols) of global K-tile g
  auto stageA = [&](int g, int h) {
    const int tile = t0 + g / KNT;
    const int k0 = (g % KNT) * 64;
    const int m0 = (tile & 7) << 8;
    const int buf = g & 1;
#pragma unroll
    for (int r = 0; r < 2; ++r) {
      int idx = r * 512 + tid;
      int row = h * 128 + (idx >> 3);
      int ch = (idx & 7) ^ (row & 7);
      gload_lds16(Ag + (size_t)(m0 + row) * Kd + k0 + ch * 8, &As[buf][row * 64 + (idx & 7) * 8]);
    }
  };
  auto stageB = [&](int g, int h) {
    const int tile = t0 + g / KNT;
    const int k0 = (g % KNT) * 64;
    const int n0 = (tile >> 3) << 8;
    const int buf = g & 1;
#pragma unroll
    for (int r = 0; r < 2; ++r) {
      int idx = r * 512 + tid;
      int row = h * 128 + (idx >> 3);
      int ch = (idx & 7) ^ (row & 7);
      gload_lds16(Bg + (size_t)(n0 + row) * Kd + k0 + ch * 8, &Bs[buf][row * 64 + (idx & 7) * 8]);
    }
  };

  bf16x8 af[4][2], bf0[2][2], bf1[2][2];
  auto readA = [&](int buf, int mh) {
#pragma unroll
    for (int q = 0; q < 4; ++q) {
      int row = wm * 128 + (mh * 4 + q) * 16 + (lane & 15);
#pragma unroll
      for (int ks = 0; ks < 2; ++ks) {
        int ch = (ks * 4 + (lane >> 4)) ^ (row & 7);
        af[q][ks] = *(const bf16x8*)(&As[buf][row * 64 + ch * 8]);
      }
    }
  };
  auto readB = [&](int buf, int nh, bf16x8 bfr[2][2]) {
#pragma unroll
    for (int p = 0; p < 2; ++p) {
      int row = wn * 64 + (nh * 2 + p) * 16 + (lane & 15);
#pragma unroll
      for (int ks = 0; ks < 2; ++ks) {
        int ch = (ks * 4 + (lane >> 4)) ^ (row & 7);
        bfr[p][ks] = *(const bf16x8*)(&Bs[buf][row * 64 + ch * 8]);
      }
    }
  };
  auto domfma = [&](int mh, int p0, bf16x8 bfr[2][2]) {
    __builtin_amdgcn_s_setprio(1);
#pragma unroll
    for (int ks = 0; ks < 2; ++ks)
#pragma unroll
      for (int q = 0; q < 4; ++q)
#pragma unroll
        for (int p = 0; p < 2; ++p)
          acc[mh * 4 + q][p0 + p] =
              __builtin_amdgcn_mfma_f32_16x16x32_bf16(af[q][ks], bfr[p][ks], acc[mh * 4 + q][p0 + p], 0, 0, 0);
    __builtin_amdgcn_s_setprio(0);
  };
  auto dump = [&](int tile) {
    const int m0 = (tile & 7) << 8;
    const int n0 = (tile >> 3) << 8;
#pragma unroll
    for (int mi = 0; mi < 8; ++mi) {
      int rbase = m0 + wm * 128 + mi * 16 + (lane >> 4) * 4;
#pragma unroll
      for (int nj = 0; nj < 4; ++nj) {
        int col = n0 + wn * 64 + nj * 16 + (lane & 15);
        if (col < Nd) {
          float bv = bias[col];
#pragma unroll
          for (int r = 0; r < 4; ++r)
            C[(size_t)(rbase + r) * ldc + col] = acc[mi][nj][r] + bv;
        }
        acc[mi][nj] = z4;
      }
    }
  };

  // ---- prologue: tile-kt0 (4 halves) + kt1 B (2 halves); oldest 8 must land ----
  stageB(0, 0); stageB(0, 1); stageA(0, 0); stageA(0, 1);
  stageB(1, 0); stageB(1, 1);
  asm volatile("s_waitcnt vmcnt(4)" ::: "memory");
  PHASE_END();

  const int iters = G / 2;
  for (int gi = 0; gi < iters; ++gi) {
    const int t1 = 2 * gi + 1, t2 = 2 * gi + 2, t3 = 2 * gi + 3;
    const bool has2 = (t2 < G);
    // phase 1: Q(m0,n0) buf0 | stage A-h0(t1)
    stageA(t1, 0);
    readA(0, 0);
    readB(0, 0, bf0);
    domfma(0, 0, bf0);
    PHASE_END();
    // phase 2: Q(m0,n1) | stage A-h1(t1)
    stageA(t1, 1);
    readB(0, 1, bf1);
    domfma(0, 2, bf1);
    PHASE_END();
    // phase 3: Q(m1,n1) | stage B-h0(t2)
    if (has2) stageB(t2, 0);
    readA(0, 1);
    domfma(1, 2, bf1);
    PHASE_END();
    // phase 4: Q(m1,n0) | stage B-h1(t2); wait t1 landed
    if (has2) stageB(t2, 1);
    readB(0, 0, bf0);
    domfma(1, 0, bf0);
    if (has2) asm volatile("s_waitcnt vmcnt(4)" ::: "memory");
    else      asm volatile("s_waitcnt vmcnt(0)" ::: "memory");
    PHASE_END();
    // phase 5: Q(m0,n0) buf1 | stage A-h0(t2)
    if (has2) stageA(t2, 0);
    readA(1, 0);
    readB(1, 0, bf0);
    domfma(0, 0, bf0);
    PHASE_END();
    // phase 6: Q(m0,n1) | stage A-h1(t2)
    if (has2) stageA(t2, 1);
    readB(1, 1, bf1);
    domfma(0, 2, bf1);
    PHASE_END();
    // phase 7: Q(m1,n1) | stage B-h0(t3)
    if (has2) stageB(t3, 0);
    readA(1, 1);
    domfma(1, 2, bf1);
    PHASE_END();
    // phase 8: Q(m1,n0) | stage B-h1(t3); wait t2 landed
    if (has2) stageB(t3, 1);
    readB(1, 0, bf0);
    domfma(1, 0, bf0);
    if (has2) asm volatile("s_waitcnt vmcnt(4)" ::: "memory");
    PHASE_END();
    // tile boundary: dump acc (overlaps next tile's in-flight stages)
    if (((2 * gi + 1) % KNT) == KNT - 1) dump(t0 + (2 * gi + 1) / KNT);
  }
}

extern "C" void kernel_launch(void* const* d_in, const int* in_sizes, int n_in,
                              void* d_out, int out_size, void* d_ws, size_t ws_size,
                              hipStream_t stream) {
  const float* sre = (const float*)d_in[0];
  const float* simg = (const float*)d_in[1];
  const float* cre = (const float*)d_in[2];
  const float* cim = (const float*)d_in[3];
  const float* W1 = (const float*)d_in[4];
  const float* b1 = (const float*)d_in[5];
  const float* W2 = (const float*)d_in[6];
  const float* b2 = (const float*)d_in[7];
  const float* W3 = (const float*)d_in[8];
  const float* b3 = (const float*)d_in[9];
  const float* W4 = (const float*)d_in[10];
  const float* b4 = (const float*)d_in[11];

  const int M = 2048, D = 512, Cc = 1000, V = 50000, K1 = 1024, H3 = 768;
  const int Npad2 = 196 * 256;  // 50176

  char* ws = (char*)d_ws;
  size_t off = 0;
  auto alloc = [&](size_t bytes) {
    char* p = ws + off;
    off = (off + bytes + 255) & ~(size_t)255;
    return p;
  };
  __hip_bfloat16* xcatb = (__hip_bfloat16*)alloc((size_t)M * K1 * 2);
  float* mag = (float*)alloc((size_t)M * D * 4);
  float* cmagT = (float*)alloc((size_t)D * Cc * 4);
  float* xn = (float*)alloc((size_t)M * 4);
  float* yn = (float*)alloc((size_t)Cc * 4);
  float* simsb = (float*)alloc((size_t)M * Cc * 4);
  __hip_bfloat16* h1b = (__hip_bfloat16*)alloc((size_t)M * 512 * 2);
  __hip_bfloat16* h2b = (__hip_bfloat16*)alloc((size_t)M * 512 * 2);
  __hip_bfloat16* h3b = (__hip_bfloat16*)alloc((size_t)M * H3 * 2);
  __hip_bfloat16* w1t = (__hip_bfloat16*)alloc((size_t)512 * K1 * 2);
  __hip_bfloat16* w2t = (__hip_bfloat16*)alloc((size_t)512 * 512 * 2);
  __hip_bfloat16* w3t = (__hip_bfloat16*)alloc((size_t)H3 * 512 * 2);
  __hip_bfloat16* w4t = (__hip_bfloat16*)alloc((size_t)Npad2 * H3 * 2);

  float* top_sims = (float*)d_out;
  float* top_idx = (float*)d_out + (size_t)M * 5;
  float* logits = (float*)d_out + (size_t)M * 5 * 2;

  // weight transposes (f32 [K,N] -> bf16 [N,K], W4 zero-padded to 50176 rows)
  k_tr<<<dim3(512 / 64, K1 / 64), dim3(256), 0, stream>>>(W1, w1t, K1, 512);
  k_tr<<<dim3(512 / 64, 512 / 64), dim3(256), 0, stream>>>(W2, w2t, 512, 512);
  k_tr<<<dim3(H3 / 64, 512 / 64), dim3(256), 0, stream>>>(W3, w3t, 512, H3);
  k_tr<<<dim3(Npad2 / 64, H3 / 64), dim3(256), 0, stream>>>(W4, w4t, H3, V);

  k_cmag<<<dim3(Cc), dim3(256), 0, stream>>>(cre, cim, cmagT, yn);
  k_mag<<<dim3(M), dim3(256), 0, stream>>>(sre, simg, mag, xcatb, xn);
  k_dots<<<dim3((Cc + 63) / 64, M / 64), dim3(256), 0, stream>>>(mag, cmagT, simsb, M, Cc, D, Cc, xn, yn);
  k_topk<<<dim3(M / 4), dim3(256), 0, stream>>>(simsb, top_sims, top_idx);

  gemm_mfma_bt<<<dim3(512 / 128, M / 128), dim3(256), 0, stream>>>(xcatb, w1t, h1b, M, 512, K1, 512, b1);
  gemm_mfma_bt<<<dim3(512 / 128, M / 128), dim3(256), 0, stream>>>(h1b, w2t, h2b, M, 512, 512, 512, b2);
  gemm_mfma_bt<<<dim3(H3 / 128, M / 128), dim3(256), 0, stream>>>(h2b, w3t, h3b, M, H3, 512, H3, b3);

  gemm_mfma8<<<dim3(256), dim3(512), 0, stream>>>(h3b, w4t, logits, b4);
}

// Round 5
// 486.684 us; speedup vs baseline: 1.3406x; 1.0087x over previous
//
#include <hip/hip_runtime.h>
#include <hip/hip_bf16.h>

#define CEPS 1e-8f

typedef __attribute__((ext_vector_type(8))) __bf16 bf16x8;
typedef __attribute__((ext_vector_type(4))) float f32x4;

__device__ __forceinline__ void gload_lds16(const void* g, void* l) {
  __builtin_amdgcn_global_load_lds((const __attribute__((address_space(1))) unsigned int*)g,
                                   (__attribute__((address_space(3))) unsigned int*)l, 16, 0, 0);
}

__device__ __forceinline__ float gelu_f(float v) {
  return 0.5f * v * (1.0f + erff(v * 0.70710678118654752f));
}

// ---------- magnitude + concat(bf16) + row norm (round-3 proven version) ----------
__global__ __launch_bounds__(256) void k_mag(const float* __restrict__ re, const float* __restrict__ im,
                                             float* __restrict__ mag, __hip_bfloat16* __restrict__ xcat,
                                             float* __restrict__ xn) {
  int row = blockIdx.x;  // 0..2047
  const float* r = re + (size_t)row * 512;
  const float* q = im + (size_t)row * 512;
  double ss = 0.0;
  for (int d = threadIdx.x; d < 512; d += 256) {
    float a = r[d], b = q[d];
    float s = __fadd_rn(__fmul_rn(a, a), __fmul_rn(b, b));  // match np rounding
    float m = __fsqrt_rn(s);
    mag[(size_t)row * 512 + d] = m;
    xcat[(size_t)row * 1024 + d] = __float2bfloat16(a);
    xcat[(size_t)row * 1024 + 512 + d] = __float2bfloat16(b);
    ss += (double)m * (double)m;
  }
  for (int off = 32; off; off >>= 1) ss += __shfl_xor(ss, off);
  __shared__ double red[4];
  int lane = threadIdx.x & 63, wave = threadIdx.x >> 6;
  if (lane == 0) red[wave] = ss;
  __syncthreads();
  if (threadIdx.x == 0) {
    double tot = red[0] + red[1] + red[2] + red[3];
    float n = (float)sqrt(tot);
    xn[row] = fmaxf(n, CEPS);
  }
}

// ---------- concept magnitude (transposed) + norms (round-3 proven version) ----------
__global__ __launch_bounds__(256) void k_cmag(const float* __restrict__ cre, const float* __restrict__ cim,
                                              float* __restrict__ cmagT, float* __restrict__ yn) {
  int c = blockIdx.x;  // 0..999
  const float* r = cre + (size_t)c * 512;
  const float* q = cim + (size_t)c * 512;
  double ss = 0.0;
  for (int d = threadIdx.x; d < 512; d += 256) {
    float a = r[d], b = q[d];
    float s = __fadd_rn(__fmul_rn(a, a), __fmul_rn(b, b));
    float m = __fsqrt_rn(s);
    cmagT[(size_t)d * 1000 + c] = m;
    ss += (double)m * (double)m;
  }
  for (int off = 32; off; off >>= 1) ss += __shfl_xor(ss, off);
  __shared__ double red[4];
  int lane = threadIdx.x & 63, wave = threadIdx.x >> 6;
  if (lane == 0) red[wave] = ss;
  __syncthreads();
  if (threadIdx.x == 0) {
    double tot = red[0] + red[1] + red[2] + red[3];
    float n = (float)sqrt(tot);
    yn[c] = fmaxf(n, CEPS);
  }
}

// ---------- dots GEMM with f64 accumulation + cosine epilogue (round-3 proven version) ----------
__global__ __launch_bounds__(256) void k_dots(const float* __restrict__ A, const float* __restrict__ Bm,
                                              float* __restrict__ Cm, int M, int N, int K, int ldc,
                                              const float* __restrict__ xn, const float* __restrict__ yn) {
  __shared__ float As[16][64];
  __shared__ float Bs[16][64];
  const int tid = threadIdx.x;
  const int m0 = blockIdx.y * 64, n0 = blockIdx.x * 64;
  const int tx = tid & 15, ty = tid >> 4;
  const int ar = tid >> 2, ak = (tid & 3) << 2;
  const int bk = tid >> 4, bn = (tid & 15) << 2;
  double acc[4][4] = {};
  for (int k0 = 0; k0 < K; k0 += 16) {
    float4 a4 = *(const float4*)(A + (size_t)(m0 + ar) * K + k0 + ak);
    As[ak + 0][ar] = a4.x; As[ak + 1][ar] = a4.y; As[ak + 2][ar] = a4.z; As[ak + 3][ar] = a4.w;
    float4 b4 = make_float4(0.f, 0.f, 0.f, 0.f);
    if (n0 + bn < N) b4 = *(const float4*)(Bm + (size_t)(k0 + bk) * N + n0 + bn);
    *(float4*)&Bs[bk][bn] = b4;
    __syncthreads();
#pragma unroll
    for (int kk = 0; kk < 16; ++kk) {
      float av[4], bv[4];
#pragma unroll
      for (int i = 0; i < 4; ++i) av[i] = As[kk][ty * 4 + i];
#pragma unroll
      for (int j = 0; j < 4; ++j) bv[j] = Bs[kk][tx * 4 + j];
#pragma unroll
      for (int i = 0; i < 4; ++i)
#pragma unroll
        for (int j = 0; j < 4; ++j)
          acc[i][j] += (double)av[i] * (double)bv[j];
    }
    __syncthreads();
  }
#pragma unroll
  for (int i = 0; i < 4; ++i) {
    int row = m0 + ty * 4 + i;
#pragma unroll
    for (int j = 0; j < 4; ++j) {
      int col = n0 + tx * 4 + j;
      if (col >= N) continue;
      double d = acc[i][j] / ((double)xn[row] * (double)yn[col]);
      Cm[(size_t)row * ldc + col] = (float)d;
    }
  }
}

// ---------- top-5 per row (one wave per row) ----------
__global__ __launch_bounds__(256) void k_topk(const float* __restrict__ sims,
                                              float* __restrict__ top_sims, float* __restrict__ top_idx) {
  int lane = threadIdx.x & 63, wave = threadIdx.x >> 6;
  int row = blockIdx.x * 4 + wave;
  const float* s = sims + (size_t)row * 1000;
  float v[16];
  int idx[16];
#pragma unroll
  for (int t = 0; t < 16; ++t) {
    int c = lane + t * 64;
    if (c < 1000) { v[t] = s[c]; idx[t] = c; }
    else { v[t] = -1e30f; idx[t] = 1 << 20; }
  }
  for (int j = 0; j < 5; ++j) {
    float bv = -1e30f; int bi = 1 << 20;
#pragma unroll
    for (int t = 0; t < 16; ++t) {
      if (v[t] > bv || (v[t] == bv && idx[t] < bi)) { bv = v[t]; bi = idx[t]; }
    }
    float rv = bv; int ri = bi;
#pragma unroll
    for (int off = 32; off; off >>= 1) {
      float ov = __shfl_xor(rv, off);
      int oi = __shfl_xor(ri, off);
      if (ov > rv || (ov == rv && oi < ri)) { rv = ov; ri = oi; }
    }
    if (lane == 0) {
      top_sims[(size_t)row * 5 + j] = rv;
      top_idx[(size_t)row * 5 + j] = (float)ri;
    }
#pragma unroll
    for (int t = 0; t < 16; ++t)
      if (idx[t] == ri) v[t] = -1e30f;
  }
}

// ---------- generic transpose + bf16 convert: W[K,N] f32 -> Wt[Nout rows][K] bf16 (zero-pad n>=N) ----------
__global__ __launch_bounds__(256) void k_tr(const float* __restrict__ W, __hip_bfloat16* __restrict__ Wt,
                                            int K, int N) {
  __shared__ float t32[64][65];
  int n0 = blockIdx.x * 64, k0 = blockIdx.y * 64;
  int tid = threadIdx.x;
  {
    int nc = tid & 15, kr4 = tid >> 4;
#pragma unroll
    for (int p = 0; p < 4; ++p) {
      int kr = p * 16 + kr4;
      int n = n0 + nc * 4;
      float4 v = make_float4(0.f, 0.f, 0.f, 0.f);
      if (n < N) v = *(const float4*)(W + (size_t)(k0 + kr) * N + n);
      t32[kr][nc * 4 + 0] = v.x; t32[kr][nc * 4 + 1] = v.y;
      t32[kr][nc * 4 + 2] = v.z; t32[kr][nc * 4 + 3] = v.w;
    }
  }
  __syncthreads();
  {
    int kc = tid & 15, nr4 = tid >> 4;
#pragma unroll
    for (int p = 0; p < 4; ++p) {
      int nr = p * 16 + nr4;
      ushort4 o;
      {
        __hip_bfloat16 h0 = __float2bfloat16(t32[kc * 4 + 0][nr]);
        __hip_bfloat16 h1 = __float2bfloat16(t32[kc * 4 + 1][nr]);
        __hip_bfloat16 h2 = __float2bfloat16(t32[kc * 4 + 2][nr]);
        __hip_bfloat16 h3 = __float2bfloat16(t32[kc * 4 + 3][nr]);
        o.x = *(unsigned short*)&h0; o.y = *(unsigned short*)&h1;
        o.z = *(unsigned short*)&h2; o.w = *(unsigned short*)&h3;
      }
      *(ushort4*)((unsigned short*)Wt + (size_t)(n0 + nr) * K + k0 + kc * 4) = o;
    }
  }
}

// ---------- 128x128 bf16 MFMA GEMM with gelu+bf16 epilogue (MLP layers) ----------
__global__ __launch_bounds__(256) void gemm_mfma_bt(const __hip_bfloat16* __restrict__ A,
                                                    const __hip_bfloat16* __restrict__ Bt,
                                                    __hip_bfloat16* __restrict__ C, int M, int N, int K,
                                                    int ldc, const float* __restrict__ bias) {
  __shared__ short Al[128 * 32];
  __shared__ short Bl[128 * 32];
  const int tid = threadIdx.x, lane = tid & 63, wave = tid >> 6;
  const int m0 = blockIdx.y * 128, n0 = blockIdx.x * 128;
  const int wr = wave >> 1, wc = wave & 1;
  f32x4 acc[4][4];
  f32x4 zero4 = {0.f, 0.f, 0.f, 0.f};
#pragma unroll
  for (int i = 0; i < 4; ++i)
#pragma unroll
    for (int j = 0; j < 4; ++j) acc[i][j] = zero4;

  const short* Ag = (const short*)A;
  const short* Bg = (const short*)Bt;
  for (int k0 = 0; k0 < K; k0 += 32) {
#pragma unroll
    for (int s = 0; s < 2; ++s) {
      int seg = wave + s * 4;
      int elem = seg * 512 + lane * 8;
      int row = elem >> 5, kk = elem & 31;
      gload_lds16(Ag + (size_t)(m0 + row) * K + k0 + kk, Al + elem);
      gload_lds16(Bg + (size_t)(n0 + row) * K + k0 + kk, Bl + elem);
    }
    __syncthreads();
    bf16x8 af[4], bfr[4];
    const int fr = lane & 15, fk = (lane >> 4) << 3;
#pragma unroll
    for (int i = 0; i < 4; ++i)
      af[i] = *(const bf16x8*)(Al + (wr * 64 + i * 16 + fr) * 32 + fk);
#pragma unroll
    for (int j = 0; j < 4; ++j)
      bfr[j] = *(const bf16x8*)(Bl + (wc * 64 + j * 16 + fr) * 32 + fk);
#pragma unroll
    for (int i = 0; i < 4; ++i)
#pragma unroll
      for (int j = 0; j < 4; ++j)
        acc[i][j] = __builtin_amdgcn_mfma_f32_16x16x32_bf16(af[i], bfr[j], acc[i][j], 0, 0, 0);
    __syncthreads();
  }
  const int fr = lane & 15, fq = lane >> 4;
#pragma unroll
  for (int j = 0; j < 4; ++j) {
    int col = n0 + wc * 64 + j * 16 + fr;
    if (col >= N) continue;
    float bv = bias[col];
#pragma unroll
    for (int i = 0; i < 4; ++i) {
      int rbase = m0 + wr * 64 + i * 16 + fq * 4;
#pragma unroll
      for (int r = 0; r < 4; ++r)
        C[(size_t)(rbase + r) * ldc + col] = __float2bfloat16(gelu_f(acc[i][j][r] + bv));
    }
  }
}

// ---------- persistent 256x256 8-phase bf16 MFMA GEMM (final layer) ----------
// M=2048 (8 mtiles), N=50000 (196 ntiles, padded B), K=768 (12 K-tiles). 256 blocks (1/CU).
// STRIDED assignment: block (xcd=bid&7, j=bid>>3) owns tiles xcd*196 + j + 32t — the 32
// blocks of an XCD sweep 32 consecutive tiles together (4 B panels = 1.6 MB, L2-resident).
// C stores are nontemporal (don't evict B panels from L2).
#define PHASE_END() do { __builtin_amdgcn_sched_barrier(0); __builtin_amdgcn_s_barrier(); __builtin_amdgcn_sched_barrier(0); } while (0)

__global__ __launch_bounds__(512, 2) void gemm_mfma8(const __hip_bfloat16* __restrict__ A,
                                                     const __hip_bfloat16* __restrict__ Bt,
                                                     float* __restrict__ C,
                                                     const float* __restrict__ bias) {
  const int KNT = 12;  // K/64
  const int Kd = 768, Nd = 50000, ldc = 50000;
  __shared__ short As[2][16384];
  __shared__ short Bs[2][16384];
  const int tid = threadIdx.x, lane = tid & 63, wave = tid >> 6;
  const int wm = wave >> 2, wn = wave & 3;

  const int xcd = blockIdx.x & 7, jb = blockIdx.x >> 3;
  const int tbase = xcd * 196 + jb;          // tile t: tbase + 32*t
  const int T = 6 + (jb < 4 ? 1 : 0);
  const int G = T * KNT;                     // even

  const short* Ag = (const short*)A;
  const short* Bg = (const short*)Bt;

  f32x4 acc[8][4];
  f32x4 z4 = {0.f, 0.f, 0.f, 0.f};
#pragma unroll
  for (int i = 0; i < 8; ++i)
#pragma unroll
    for (int j = 0; j < 4; ++j) acc[i][j] = z4;

  auto stageA = [&](int g, int h) {
    const int tile = tbase + (g / KNT) * 32;
    const int k0 = (g % KNT) * 64;
    const int m0 = (tile & 7) << 8;
    const int buf = g & 1;
#pragma unroll
    for (int r = 0; r < 2; ++r) {
      int idx = r * 512 + tid;
      int row = h * 128 + (idx >> 3);
      int ch = (idx & 7) ^ (row & 7);
      gload_lds16(Ag + (size_t)(m0 + row) * Kd + k0 + ch * 8, &As[buf][row * 64 + (idx & 7) * 8]);
    }
  };
  auto stageB = [&](int g, int h) {
    const int tile = tbase + (g / KNT) * 32;
    const int k0 = (g % KNT) * 64;
    const int n0 = (tile >> 3) << 8;
    const int buf = g & 1;
#pragma unroll
    for (int r = 0; r < 2; ++r) {
      int idx = r * 512 + tid;
      int row = h * 128 + (idx >> 3);
      int ch = (idx & 7) ^ (row & 7);
      gload_lds16(Bg + (size_t)(n0 + row) * Kd + k0 + ch * 8, &Bs[buf][row * 64 + (idx & 7) * 8]);
    }
  };

  bf16x8 af[4][2], bf0[2][2], bf1[2][2];
  auto readA = [&](int buf, int mh) {
#pragma unroll
    for (int q = 0; q < 4; ++q) {
      int row = wm * 128 + (mh * 4 + q) * 16 + (lane & 15);
#pragma unroll
      for (int ks = 0; ks < 2; ++ks) {
        int ch = (ks * 4 + (lane >> 4)) ^ (row & 7);
        af[q][ks] = *(const bf16x8*)(&As[buf][row * 64 + ch * 8]);
      }
    }
  };
  auto readB = [&](int buf, int nh, bf16x8 bfr[2][2]) {
#pragma unroll
    for (int p = 0; p < 2; ++p) {
      int row = wn * 64 + (nh * 2 + p) * 16 + (lane & 15);
#pragma unroll
      for (int ks = 0; ks < 2; ++ks) {
        int ch = (ks * 4 + (lane >> 4)) ^ (row & 7);
        bfr[p][ks] = *(const bf16x8*)(&Bs[buf][row * 64 + ch * 8]);
      }
    }
  };
  auto domfma = [&](int mh, int p0, bf16x8 bfr[2][2]) {
    __builtin_amdgcn_s_setprio(1);
#pragma unroll
    for (int ks = 0; ks < 2; ++ks)
#pragma unroll
      for (int q = 0; q < 4; ++q)
#pragma unroll
        for (int p = 0; p < 2; ++p)
          acc[mh * 4 + q][p0 + p] =
              __builtin_amdgcn_mfma_f32_16x16x32_bf16(af[q][ks], bfr[p][ks], acc[mh * 4 + q][p0 + p], 0, 0, 0);
    __builtin_amdgcn_s_setprio(0);
  };
  auto dump = [&](int tile) {
    const int m0 = (tile & 7) << 8;
    const int n0 = (tile >> 3) << 8;
#pragma unroll
    for (int mi = 0; mi < 8; ++mi) {
      int rbase = m0 + wm * 128 + mi * 16 + (lane >> 4) * 4;
#pragma unroll
      for (int nj = 0; nj < 4; ++nj) {
        int col = n0 + wn * 64 + nj * 16 + (lane & 15);
        if (col < Nd) {
          float bv = bias[col];
#pragma unroll
          for (int r = 0; r < 4; ++r)
            __builtin_nontemporal_store(acc[mi][nj][r] + bv, &C[(size_t)(rbase + r) * ldc + col]);
        }
        acc[mi][nj] = z4;
      }
    }
  };

  stageB(0, 0); stageB(0, 1); stageA(0, 0); stageA(0, 1);
  stageB(1, 0); stageB(1, 1);
  asm volatile("s_waitcnt vmcnt(4)" ::: "memory");
  PHASE_END();

  const int iters = G / 2;
  for (int gi = 0; gi < iters; ++gi) {
    const int t1 = 2 * gi + 1, t2 = 2 * gi + 2, t3 = 2 * gi + 3;
    const bool has2 = (t2 < G);
    // phase 1: Q(m0,n0) buf0 | stage A-h0(t1)
    stageA(t1, 0);
    readA(0, 0);
    readB(0, 0, bf0);
    domfma(0, 0, bf0);
    PHASE_END();
    // phase 2: Q(m0,n1) | stage A-h1(t1)
    stageA(t1, 1);
    readB(0, 1, bf1);
    domfma(0, 2, bf1);
    PHASE_END();
    // phase 3: Q(m1,n1) | stage B-h0(t2)
    if (has2) stageB(t2, 0);
    readA(0, 1);
    domfma(1, 2, bf1);
    PHASE_END();
    // phase 4: Q(m1,n0) | stage B-h1(t2); wait t1 landed
    if (has2) stageB(t2, 1);
    readB(0, 0, bf0);
    domfma(1, 0, bf0);
    if (has2) asm volatile("s_waitcnt vmcnt(4)" ::: "memory");
    else      asm volatile("s_waitcnt vmcnt(0)" ::: "memory");
    PHASE_END();
    // phase 5: Q(m0,n0) buf1 | stage A-h0(t2)
    if (has2) stageA(t2, 0);
    readA(1, 0);
    readB(1, 0, bf0);
    domfma(0, 0, bf0);
    PHASE_END();
    // phase 6: Q(m0,n1) | stage A-h1(t2)
    if (has2) stageA(t2, 1);
    readB(1, 1, bf1);
    domfma(0, 2, bf1);
    PHASE_END();
    // phase 7: Q(m1,n1) | stage B-h0(t3)
    if (has2) stageB(t3, 0);
    readA(1, 1);
    domfma(1, 2, bf1);
    PHASE_END();
    // phase 8: Q(m1,n0) | stage B-h1(t3); wait t2 landed
    if (has2) stageB(t3, 1);
    readB(1, 0, bf0);
    domfma(1, 0, bf0);
    if (has2) asm volatile("s_waitcnt vmcnt(4)" ::: "memory");
    PHASE_END();
    if (((2 * gi + 1) % KNT) == KNT - 1) dump(tbase + ((2 * gi + 1) / KNT) * 32);
  }
}

extern "C" void kernel_launch(void* const* d_in, const int* in_sizes, int n_in,
                              void* d_out, int out_size, void* d_ws, size_t ws_size,
                              hipStream_t stream) {
  const float* sre = (const float*)d_in[0];
  const float* simg = (const float*)d_in[1];
  const float* cre = (const float*)d_in[2];
  const float* cim = (const float*)d_in[3];
  const float* W1 = (const float*)d_in[4];
  const float* b1 = (const float*)d_in[5];
  const float* W2 = (const float*)d_in[6];
  const float* b2 = (const float*)d_in[7];
  const float* W3 = (const float*)d_in[8];
  const float* b3 = (const float*)d_in[9];
  const float* W4 = (const float*)d_in[10];
  const float* b4 = (const float*)d_in[11];

  const int M = 2048, D = 512, Cc = 1000, V = 50000, K1 = 1024, H3 = 768;
  const int Npad2 = 196 * 256;  // 50176

  char* ws = (char*)d_ws;
  size_t off = 0;
  auto alloc = [&](size_t bytes) {
    char* p = ws + off;
    off = (off + bytes + 255) & ~(size_t)255;
    return p;
  };
  __hip_bfloat16* xcatb = (__hip_bfloat16*)alloc((size_t)M * K1 * 2);
  float* mag = (float*)alloc((size_t)M * D * 4);
  float* cmagT = (float*)alloc((size_t)D * Cc * 4);
  float* xn = (float*)alloc((size_t)M * 4);
  float* yn = (float*)alloc((size_t)Cc * 4);
  float* simsb = (float*)alloc((size_t)M * Cc * 4);
  __hip_bfloat16* h1b = (__hip_bfloat16*)alloc((size_t)M * 512 * 2);
  __hip_bfloat16* h2b = (__hip_bfloat16*)alloc((size_t)M * 512 * 2);
  __hip_bfloat16* h3b = (__hip_bfloat16*)alloc((size_t)M * H3 * 2);
  __hip_bfloat16* w1t = (__hip_bfloat16*)alloc((size_t)512 * K1 * 2);
  __hip_bfloat16* w2t = (__hip_bfloat16*)alloc((size_t)512 * 512 * 2);
  __hip_bfloat16* w3t = (__hip_bfloat16*)alloc((size_t)H3 * 512 * 2);
  __hip_bfloat16* w4t = (__hip_bfloat16*)alloc((size_t)Npad2 * H3 * 2);

  float* top_sims = (float*)d_out;
  float* top_idx = (float*)d_out + (size_t)M * 5;
  float* logits = (float*)d_out + (size_t)M * 5 * 2;

  k_tr<<<dim3(512 / 64, K1 / 64), dim3(256), 0, stream>>>(W1, w1t, K1, 512);
  k_tr<<<dim3(512 / 64, 512 / 64), dim3(256), 0, stream>>>(W2, w2t, 512, 512);
  k_tr<<<dim3(H3 / 64, 512 / 64), dim3(256), 0, stream>>>(W3, w3t, 512, H3);
  k_tr<<<dim3(Npad2 / 64, H3 / 64), dim3(256), 0, stream>>>(W4, w4t, H3, V);

  k_cmag<<<dim3(Cc), dim3(256), 0, stream>>>(cre, cim, cmagT, yn);
  k_mag<<<dim3(M), dim3(256), 0, stream>>>(sre, simg, mag, xcatb, xn);
  k_dots<<<dim3((Cc + 63) / 64, M / 64), dim3(256), 0, stream>>>(mag, cmagT, simsb, M, Cc, D, Cc, xn, yn);
  k_topk<<<dim3(M / 4), dim3(256), 0, stream>>>(simsb, top_sims, top_idx);

  gemm_mfma_bt<<<dim3(512 / 128, M / 128), dim3(256), 0, stream>>>(xcatb, w1t, h1b, M, 512, K1, 512, b1);
  gemm_mfma_bt<<<dim3(512 / 128, M / 128), dim3(256), 0, stream>>>(h1b, w2t, h2b, M, 512, 512, 512, b2);
  gemm_mfma_bt<<<dim3(H3 / 128, M / 128), dim3(256), 0, stream>>>(h2b, w3t, h3b, M, H3, 512, H3, b3);

  gemm_mfma8<<<dim3(256), dim3(512), 0, stream>>>(h3b, w4t, logits, b4);
}